// Round 1
// baseline (689.624 us; speedup 1.0000x reference)
//
#include <hip/hip_runtime.h>

// GCN 2-layer: out = GCNConv(relu(GCNConv(x, W1, b1)), W2, b2)
// N=100000 nodes, E=1600000 edges, dims 64 -> 48 -> 32, fp32 throughout.

#define NN 100000
#define NE 1600000

// deg[i] = 1.0 (self-loop contribution)
__global__ void k_init_deg(float* __restrict__ deg) {
    int i = blockIdx.x * blockDim.x + threadIdx.x;
    if (i < NN) deg[i] = 1.0f;
}

// deg[dst[e]] += 1
__global__ void k_count(const int* __restrict__ dst, float* __restrict__ deg) {
    int i = blockIdx.x * blockDim.x + threadIdx.x;
    if (i < NE) unsafeAtomicAdd(&deg[dst[i]], 1.0f);
}

// deg -> 1/sqrt(deg)  (deg >= 1 always, matches reference where(deg>0, rsqrt(max(deg,1)),0))
__global__ void k_rsqrt(float* __restrict__ deg) {
    int i = blockIdx.x * blockDim.x + threadIdx.x;
    if (i < NN) deg[i] = 1.0f / sqrtf(deg[i]);
}

// H[M,NC] = f(X[M,K]) @ W[K,NC]; f = identity, or relu(x + bin) when RELU_IN
// (fuses the layer-1 bias+relu into the layer-2 GEMM input read).
template <int K, int NC, bool RELU_IN>
__global__ void k_gemm(const float* __restrict__ X, const float* __restrict__ W,
                       const float* __restrict__ bin, float* __restrict__ H, int M) {
    __shared__ float w[K * NC];
    __shared__ float bb[K];
    for (int i = threadIdx.x; i < K * NC; i += blockDim.x) w[i] = W[i];
    if (RELU_IN)
        for (int i = threadIdx.x; i < K; i += blockDim.x) bb[i] = bin[i];
    __syncthreads();
    int idx = blockIdx.x * blockDim.x + threadIdx.x;
    if (idx >= M * NC) return;
    int r = idx / NC, c = idx - r * NC;
    const float* xr = X + (size_t)r * K;
    float acc = 0.f;
#pragma unroll
    for (int k = 0; k < K; ++k) {
        float v = xr[k];
        if (RELU_IN) v = fmaxf(v + bb[k], 0.f);
        acc = fmaf(v, w[k * NC + c], acc);
    }
    H[idx] = acc;
}

// out[i,f] = H[i,f]*dinv[i]^2 (+ b[f])   -- self-loop message, initializes accumulator
template <int NC, bool BIAS>
__global__ void k_self(const float* __restrict__ H, const float* __restrict__ dinv,
                       const float* __restrict__ b, float* __restrict__ out, int M) {
    int idx = blockIdx.x * blockDim.x + threadIdx.x;
    if (idx >= M * NC) return;
    int r = idx / NC, c = idx - r * NC;
    float d = dinv[r];
    float v = H[idx] * d * d;
    if (BIAS) v += b[c];
    out[idx] = v;
}

// agg[dst,f] += H[src,f] * dinv[src]*dinv[dst], one thread per (edge, feature)
template <int NC>
__global__ void k_scatter(const float* __restrict__ H, const int* __restrict__ src,
                          const int* __restrict__ dst, const float* __restrict__ dinv,
                          float* __restrict__ agg) {
    int idx = blockIdx.x * blockDim.x + threadIdx.x;
    if (idx >= NE * NC) return;
    int e = idx / NC, f = idx - e * NC;
    int s = src[e], d = dst[e];
    float nrm = dinv[s] * dinv[d];
    unsafeAtomicAdd(&agg[d * NC + f], H[s * NC + f] * nrm);
}

extern "C" void kernel_launch(void* const* d_in, const int* in_sizes, int n_in,
                              void* d_out, int out_size, void* d_ws, size_t ws_size,
                              hipStream_t stream) {
    const float* x  = (const float*)d_in[0];
    const int*   ei = (const int*)d_in[1];   // [2, NE] int32 (jax x64 disabled)
    const float* W1 = (const float*)d_in[2];
    const float* b1 = (const float*)d_in[3];
    const float* W2 = (const float*)d_in[4];
    const float* b2 = (const float*)d_in[5];
    float* out = (float*)d_out;

    const int* src = ei;
    const int* dst = ei + NE;

    // workspace: dinv [100096 aligned] | h (N*48) | agg1 (N*48); h2 reuses h
    float* dinv = (float*)d_ws;
    float* h    = dinv + 100096;
    float* agg1 = h + (size_t)NN * 48;
    float* h2   = h;  // h dead after scatter1; gemm2 output goes here

    const int B = 256;
    // degree + dinv
    k_init_deg<<<(NN + B - 1) / B, B, 0, stream>>>(dinv);
    k_count<<<(NE + B - 1) / B, B, 0, stream>>>(dst, dinv);
    k_rsqrt<<<(NN + B - 1) / B, B, 0, stream>>>(dinv);

    // layer 1: h = x @ W1
    k_gemm<64, 48, false><<<(NN * 48 + B - 1) / B, B, 0, stream>>>(x, W1, nullptr, h, NN);
    // agg1 = self-loop messages (also initializes poisoned ws)
    k_self<48, false><<<(NN * 48 + B - 1) / B, B, 0, stream>>>(h, dinv, nullptr, agg1, NN);
    // agg1 += edge messages
    k_scatter<48><<<(NE * 48 + B - 1) / B, B, 0, stream>>>(h, src, dst, dinv, agg1);

    // layer 2: h2 = relu(agg1 + b1) @ W2   (bias+relu fused into GEMM input)
    k_gemm<48, 32, true><<<(NN * 32 + B - 1) / B, B, 0, stream>>>(agg1, W2, b1, h2, NN);
    // out = self-loop messages + b2
    k_self<32, true><<<(NN * 32 + B - 1) / B, B, 0, stream>>>(h2, dinv, b2, out, NN);
    // out += edge messages
    k_scatter<32><<<(NE * 32 + B - 1) / B, B, 0, stream>>>(h2, src, dst, dinv, out);
}

// Round 2
// 575.581 us; speedup vs baseline: 1.1981x; 1.1981x over previous
//
#include <hip/hip_runtime.h>

// GCN 2-layer via device-built dst-CSR (no fp32 atomics).
// out = GCNConv(relu(GCNConv(x,W1,b1)), W2, b2); N=100k, E=1.6M, 64->48->32.

#define NN 100000
#define NE 1600000
#define SCAN_B 1024
#define NBLK ((NN + SCAN_B - 1) / SCAN_B)   // 98

__global__ void k_zero_cnt(int* __restrict__ cnt) {
    int i = blockIdx.x * blockDim.x + threadIdx.x;
    if (i < NN) cnt[i] = 0;
}

__global__ void k_count(const int* __restrict__ dst, int* __restrict__ cnt) {
    int i = blockIdx.x * blockDim.x + threadIdx.x;
    if (i < NE) atomicAdd(&cnt[dst[i]], 1);
}

// per-block exclusive scan of cnt -> lscan; block totals -> bsum
__global__ void k_scan1(const int* __restrict__ cnt, int* __restrict__ lscan,
                        int* __restrict__ bsum) {
    __shared__ int sm[SCAN_B];
    int t = threadIdx.x, i = blockIdx.x * SCAN_B + t;
    int v = (i < NN) ? cnt[i] : 0;
    sm[t] = v; __syncthreads();
    for (int off = 1; off < SCAN_B; off <<= 1) {
        int xv = (t >= off) ? sm[t - off] : 0;
        __syncthreads();
        sm[t] += xv;
        __syncthreads();
    }
    if (i < NN) lscan[i] = sm[t] - v;          // exclusive
    if (t == SCAN_B - 1) bsum[blockIdx.x] = sm[t];
}

// single-block exclusive scan of the 98 block sums; also row_ptr[NN] = NE
__global__ void k_scan2(int* __restrict__ bsum, int* __restrict__ row_ptr) {
    __shared__ int sm[128];
    int t = threadIdx.x;
    int v = (t < NBLK) ? bsum[t] : 0;
    sm[t] = v; __syncthreads();
    for (int off = 1; off < 128; off <<= 1) {
        int xv = (t >= off) ? sm[t - off] : 0;
        __syncthreads();
        sm[t] += xv;
        __syncthreads();
    }
    if (t < NBLK) bsum[t] = sm[t] - v;
    if (t == 0) row_ptr[NN] = NE;
}

// row_ptr[i] = lscan[i] + bsum[blk]; cursor = copy; dinv = rsqrt(deg+1)
__global__ void k_scan3(const int* __restrict__ cnt, const int* __restrict__ lscan,
                        const int* __restrict__ bsum, int* __restrict__ row_ptr,
                        int* __restrict__ cursor, float* __restrict__ dinv) {
    int i = blockIdx.x * blockDim.x + threadIdx.x;
    if (i >= NN) return;
    int rp = lscan[i] + bsum[i / SCAN_B];
    row_ptr[i] = rp;
    cursor[i]  = rp;
    dinv[i] = rsqrtf((float)(cnt[i] + 1));     // +1 self-loop; deg>=1 always
}

__global__ void k_fill(const int* __restrict__ src, const int* __restrict__ dst,
                       int* __restrict__ cursor, int* __restrict__ csr_src) {
    int e = blockIdx.x * blockDim.x + threadIdx.x;
    if (e >= NE) return;
    int p = atomicAdd(&cursor[dst[e]], 1);
    csr_src[p] = src[e];
}

// Hs[M,NC] = f(X[M,K]) @ W[K,NC] * dinv[row]; f = relu(x+bin) when RELU_IN
template <int K, int NC, bool RELU_IN>
__global__ void k_gemm(const float* __restrict__ X, const float* __restrict__ W,
                       const float* __restrict__ bin, const float* __restrict__ dinv,
                       float* __restrict__ H, int M) {
    __shared__ float w[K * NC];
    __shared__ float bb[K];
    for (int i = threadIdx.x; i < K * NC; i += blockDim.x) w[i] = W[i];
    if (RELU_IN)
        for (int i = threadIdx.x; i < K; i += blockDim.x) bb[i] = bin[i];
    __syncthreads();
    int idx = blockIdx.x * blockDim.x + threadIdx.x;
    if (idx >= M * NC) return;
    int r = idx / NC, c = idx - r * NC;
    const float* xr = X + (size_t)r * K;
    float acc = 0.f;
#pragma unroll
    for (int k = 0; k < K; ++k) {
        float v = xr[k];
        if (RELU_IN) v = fmaxf(v + bb[k], 0.f);
        acc = fmaf(v, w[k * NC + c], acc);
    }
    H[idx] = acc * dinv[r];
}

// out[i,f] = dinv[i] * (Hs[i,f] + sum_{e in CSR row i} Hs[src_e, f])  (+ b[f])
template <int NC, bool BIAS>
__global__ void k_agg(const float* __restrict__ Hs, const int* __restrict__ row_ptr,
                      const int* __restrict__ csr_src, const float* __restrict__ dinv,
                      const float* __restrict__ b, float* __restrict__ out) {
    int idx = blockIdx.x * blockDim.x + threadIdx.x;
    if (idx >= NN * NC) return;
    int r = idx / NC, f = idx - r * NC;
    float acc = Hs[idx];                        // self-loop (Hs already * dinv[src])
    int e0 = row_ptr[r], e1 = row_ptr[r + 1];
    for (int e = e0; e < e1; ++e) {
        int s = csr_src[e];
        acc += Hs[(size_t)s * NC + f];
    }
    float v = acc * dinv[r];
    if (BIAS) v += b[f];
    out[idx] = v;
}

extern "C" void kernel_launch(void* const* d_in, const int* in_sizes, int n_in,
                              void* d_out, int out_size, void* d_ws, size_t ws_size,
                              hipStream_t stream) {
    const float* x  = (const float*)d_in[0];
    const int*   ei = (const int*)d_in[1];   // [2,NE] int32
    const float* W1 = (const float*)d_in[2];
    const float* b1 = (const float*)d_in[3];
    const float* W2 = (const float*)d_in[4];
    const float* b2 = (const float*)d_in[5];
    float* out = (float*)d_out;

    const int* src = ei;
    const int* dst = ei + NE;

    // workspace layout (4-byte elems, 256B-ish aligned chunks)
    char* p = (char*)d_ws;
    auto take = [&](size_t elems) { void* q = p; p += ((elems * 4 + 255) & ~255ull); return q; };
    int*   cnt     = (int*)take(NN);
    int*   lscan   = (int*)take(NN);
    int*   bsum    = (int*)take(256);
    int*   row_ptr = (int*)take(NN + 1);
    int*   cursor  = (int*)take(NN);
    float* dinv    = (float*)take(NN);
    int*   csr_src = (int*)take(NE);
    float* Hs      = (float*)take((size_t)NN * 48);
    float* agg1    = (float*)take((size_t)NN * 48);
    float* Hs2     = Hs;   // Hs dead after agg1; reuse for layer-2 transform

    const int B = 256;
    // --- CSR build + dinv ---
    k_zero_cnt<<<(NN + B - 1) / B, B, 0, stream>>>(cnt);
    k_count<<<(NE + B - 1) / B, B, 0, stream>>>(dst, cnt);
    k_scan1<<<NBLK, SCAN_B, 0, stream>>>(cnt, lscan, bsum);
    k_scan2<<<1, 128, 0, stream>>>(bsum, row_ptr);
    k_scan3<<<(NN + B - 1) / B, B, 0, stream>>>(cnt, lscan, bsum, row_ptr, cursor, dinv);
    k_fill<<<(NE + B - 1) / B, B, 0, stream>>>(src, dst, cursor, csr_src);

    // --- layer 1 ---
    k_gemm<64, 48, false><<<(NN * 48 + B - 1) / B, B, 0, stream>>>(x, W1, nullptr, dinv, Hs, NN);
    k_agg<48, false><<<(NN * 48 + B - 1) / B, B, 0, stream>>>(Hs, row_ptr, csr_src, dinv, nullptr, agg1);

    // --- layer 2 (bias1+relu fused into GEMM input read) ---
    k_gemm<48, 32, true><<<(NN * 32 + B - 1) / B, B, 0, stream>>>(agg1, W2, b1, dinv, Hs2, NN);
    k_agg<32, true><<<(NN * 32 + B - 1) / B, B, 0, stream>>>(Hs2, row_ptr, csr_src, dinv, b2, out);
}